// Round 1
// baseline (199.099 us; speedup 1.0000x reference)
//
#include <hip/hip_runtime.h>
#include <cmath>

// Shapes fixed by the reference: data [32,128,80,80] int32, scale 0.0625.
#define NB  32
#define NC  128
#define NHW 6400          // 80*80, contiguous per (b,c)
#define PIX 64            // pixels per block
#define TPB 256           // 4 waves; each wave = 16 pixels x all 128 channels

typedef float vfloat4 __attribute__((ext_vector_type(4)));  // native vec for NT store

// Wave-local softmax: lane bits [1:0] = quad-in-wave, bits [5:2] = kq.
// Lane owns channels {kq, kq+16, ..., kq+112} x 4 pixels (one int4).
// Channel reductions (max, sum) are wave-internal via __shfl_xor over lane
// bits 2..5 -> exact int max/add, NO reduction barriers. The single barrier
// only publishes the LUTs. Waves retire independently -> memory pipe stays fed.

__global__ __launch_bounds__(TPB) void qsoftmax_kernel(
    const int* __restrict__ data,
    const float* __restrict__ dscale,
    float* __restrict__ out) {
#pragma clang fp contract(off)
  __shared__ int   exp_tab[256];    // quantized exp as function of j = qmax - data
  __shared__ float recip_tab[256];  // quantized 1/v table, region (0.1, 250)

  const int t   = threadIdx.x;
  const int l   = t & 63;           // lane in wave
  const int w   = t >> 6;           // wave id 0..3
  const int kq  = (l >> 2) & 15;    // channel group: channels kq + 16*i
  const int qw  = (w << 2) | (l & 3);  // quad index within block, 0..15

  const int blk  = blockIdx.x;
  const int b    = blk / (NHW / PIX);
  const int hw0  = (blk % (NHW / PIX)) * PIX;
  const int base4 = b * NC * (NHW / 4) + (hw0 >> 2) + qw;   // int4 index

  const float ds = dscale[0];  // 0.0625

  // ---- build LUTs (identical math to the verified version; do not touch) ----
  {
    const float EXP_SCALE_F = (float)(2.0 / 65535.0);
    float x = (float)(-t) * ds;
    float e;
    if (x >= 0.0f) {
      float y0 = expf(0.0f), y1 = expf(1.0f);
      e = rintf((y0 + x * ((y1 - y0) / 1.0f)) / EXP_SCALE_F);
    } else if (x >= -10.0f) {
      float delta = 10.0f / 255.0f;
      float idxf = rintf((x + 10.0f) * 25.5f);
      idxf = fminf(fmaxf(idxf, 0.0f), 255.0f);
      float xs = -10.0f + idxf * delta;
      e = rintf((float)exp((double)xs) / EXP_SCALE_F);
    } else {
      float delta = 10.0f / 255.0f;
      float idxf = rintf((x + 20.0f) * 25.5f);
      idxf = fminf(fmaxf(idxf, 0.0f), 255.0f);
      float xs = -20.0f + idxf * delta;
      e = rintf((float)exp((double)xs) / EXP_SCALE_F);
    }
    e = fminf(fmaxf(e, -32768.0f), 32767.0f);
    exp_tab[t] = (int)e;

    const float RECIP_SCALE_F = (float)((1.0 / 0.1) * 2.0 / 65535.0);
    float deltar = (250.0f - 0.1f) / 255.0f;
    float xs = 0.1f + (float)t * deltar;
    float r = rintf((1.0f / xs) / RECIP_SCALE_F);
    r = fminf(fmaxf(r, -32768.0f), 32767.0f);
    recip_tab[t] = r;
  }
  __syncthreads();   // the ONLY block-wide barrier: LUTs are now visible

  // ---- load 8 channels x 4 pixels; pack to 4x int8 per int; local max ----
  const int4* g4 = (const int4*)data;
  int pd[8];                         // packed raw data, 8 VGPRs
  int4 m = make_int4(-128, -128, -128, -128);
#pragma unroll
  for (int i = 0; i < 8; ++i) {
    int4 v = g4[base4 + (16 * i + kq) * (NHW / 4)];
    m.x = max(m.x, v.x); m.y = max(m.y, v.y);
    m.z = max(m.z, v.z); m.w = max(m.w, v.w);
    pd[i] = (v.x & 255) | ((v.y & 255) << 8) | ((v.z & 255) << 16) |
            (int)((unsigned)(v.w & 255) << 24);
  }

  // ---- wave all-reduce max over kq (lane bits 2..5); exact int max ----
#pragma unroll
  for (int xm = 4; xm <= 32; xm <<= 1) {
    m.x = max(m.x, __shfl_xor(m.x, xm, 64));
    m.y = max(m.y, __shfl_xor(m.y, xm, 64));
    m.z = max(m.z, __shfl_xor(m.z, xm, 64));
    m.w = max(m.w, __shfl_xor(m.w, xm, 64));
  }

  // ---- exp LUT gather + pack exp (u16 pairs) + channel partial sum ----
  int pe[16];                        // packed exp, 16 VGPRs
  int4 s = make_int4(0, 0, 0, 0);
#pragma unroll
  for (int i = 0; i < 8; ++i) {
    int pdv = pd[i];
    int c0 = (pdv << 24) >> 24;
    int c1 = (pdv << 16) >> 24;
    int c2 = (pdv << 8) >> 24;
    int c3 = pdv >> 24;
    int e0 = exp_tab[m.x - c0];      // j guaranteed in [0,255]
    int e1 = exp_tab[m.y - c1];
    int e2 = exp_tab[m.z - c2];
    int e3 = exp_tab[m.w - c3];
    s.x += e0; s.y += e1; s.z += e2; s.w += e3;
    pe[2 * i]     = e0 | (e1 << 16); // e in [0,32767] -> fits u16, sign-safe
    pe[2 * i + 1] = e2 | (e3 << 16);
  }

  // ---- wave all-reduce sum over kq (lane bits 2..5); exact int add ----
#pragma unroll
  for (int xm = 4; xm <= 32; xm <<= 1) {
    s.x += __shfl_xor(s.x, xm, 64);
    s.y += __shfl_xor(s.y, xm, 64);
    s.z += __shfl_xor(s.z, xm, 64);
    s.w += __shfl_xor(s.w, xm, 64);
  }

  // ---- per-lane recip (redundant across kq lanes; identical values) ----
  const float DIV_SCALE_F = (float)((2.0 / 65535.0) * 128.0); // exp_scale * 2^7
  const float RIDX_K_F    = (float)(255.0 / (250.0 - 0.1));
  float rq[4];
  {
    int tv[4] = {s.x, s.y, s.z, s.w};
#pragma unroll
    for (int j = 0; j < 4; ++j) {
      float ss = rintf((float)tv[j] * 0.0078125f);
      ss = fminf(fmaxf(ss, -32768.0f), 32767.0f);
      float v = ss * DIV_SCALE_F;
      float idxf = rintf((v - 0.1f) * RIDX_K_F);
      idxf = fminf(fmaxf(idxf, 0.0f), 255.0f);
      rq[j] = recip_tab[(int)idxf];
    }
  }

  // ---- epilogue: out = clip(round((e*r)*K), -128, 127) * OUT_SCALE ----
  const float K_F = (float)((2.0 / 65535.0) * ((1.0 / 0.1) * 2.0 / 65535.0) / (2.0 / 255.0));
  const float OUT_SCALE_F = (float)(2.0 / 255.0);
  vfloat4* o4 = (vfloat4*)out;
#pragma unroll
  for (int i = 0; i < 8; ++i) {
    int pa = pe[2 * i], pb = pe[2 * i + 1];
    float e0 = (float)(pa & 0xFFFF);
    float e1 = (float)(pa >> 16);
    float e2 = (float)(pb & 0xFFFF);
    float e3 = (float)(pb >> 16);
    vfloat4 o;
    o.x = fminf(fmaxf(rintf((e0 * rq[0]) * K_F), -128.0f), 127.0f) * OUT_SCALE_F;
    o.y = fminf(fmaxf(rintf((e1 * rq[1]) * K_F), -128.0f), 127.0f) * OUT_SCALE_F;
    o.z = fminf(fmaxf(rintf((e2 * rq[2]) * K_F), -128.0f), 127.0f) * OUT_SCALE_F;
    o.w = fminf(fmaxf(rintf((e3 * rq[3]) * K_F), -128.0f), 127.0f) * OUT_SCALE_F;
    __builtin_nontemporal_store(o, &o4[base4 + (16 * i + kq) * (NHW / 4)]);
  }
}

extern "C" void kernel_launch(void* const* d_in, const int* in_sizes, int n_in,
                              void* d_out, int out_size, void* d_ws, size_t ws_size,
                              hipStream_t stream) {
  const int* data     = (const int*)d_in[0];
  const float* dscale = (const float*)d_in[1];
  float* out          = (float*)d_out;
  (void)in_sizes; (void)n_in; (void)d_ws; (void)ws_size; (void)out_size;

  dim3 grid(NB * (NHW / PIX));   // 32 * 100 = 3200 blocks
  qsoftmax_kernel<<<grid, TPB, 0, stream>>>(data, dscale, out);
}

// Round 2
// 189.485 us; speedup vs baseline: 1.0507x; 1.0507x over previous
//
#include <hip/hip_runtime.h>
#include <cmath>

// Shapes fixed by the reference: data [32,128,80,80] int32, scale 0.0625.
#define NB  32
#define NC  128
#define NHW 6400          // 80*80, contiguous per (b,c)
#define PIX 64            // pixels per block
#define TPB 256           // 16 "k" channel-groups x 16 pixel-quads

typedef float vfloat4 __attribute__((ext_vector_type(4)));

// Thread t: k = t>>4 owns channels {k, k+16, ..., k+112};
//           p4 = t&15 owns pixels {4*p4 .. 4*p4+3} (one int4/float4 per channel).
// 16 consecutive lanes (p4) cover 256 B contiguous per row -> full-line HBM
// writes (round-1 showed 64 B segments amplify WRITE_SIZE +19%).
// Stores are PLAIN (cached): output fits in L3 alongside the input; letting
// stores complete at L2/L3 frees wave slots instead of draining to HBM at
// s_endpgm (round-0 used nontemporal stores -> store-drain backpressure).

__global__ __launch_bounds__(TPB) void qsoftmax_kernel(
    const int* __restrict__ data,
    const float* __restrict__ dscale,
    float* __restrict__ out) {
#pragma clang fp contract(off)
  __shared__ int   exp_tab[256];    // quantized exp as function of j = qmax - data
  __shared__ float recip_tab[256];  // quantized 1/v table, region (0.1, 250)
  __shared__ int4  red_m[16][16];   // [k][p4] partial max
  __shared__ int4  red_s[16][16];   // [k][p4] partial sum

  const int t  = threadIdx.x;
  const int k  = t >> 4;
  const int p4 = t & 15;

  const int blk  = blockIdx.x;
  const int b    = blk / (NHW / PIX);
  const int hw0  = (blk % (NHW / PIX)) * PIX;
  const int base4 = b * NC * (NHW / 4) + (hw0 >> 2);   // int4 index

  const float ds = dscale[0];  // 0.0625

  // ---- build LUTs (identical math to the verified version; do not touch) ----
  {
    const float EXP_SCALE_F = (float)(2.0 / 65535.0);
    float x = (float)(-t) * ds;
    float e;
    if (x >= 0.0f) {
      float y0 = expf(0.0f), y1 = expf(1.0f);
      e = rintf((y0 + x * ((y1 - y0) / 1.0f)) / EXP_SCALE_F);
    } else if (x >= -10.0f) {
      float delta = 10.0f / 255.0f;
      float idxf = rintf((x + 10.0f) * 25.5f);
      idxf = fminf(fmaxf(idxf, 0.0f), 255.0f);
      float xs = -10.0f + idxf * delta;
      e = rintf((float)exp((double)xs) / EXP_SCALE_F);
    } else {
      float delta = 10.0f / 255.0f;
      float idxf = rintf((x + 20.0f) * 25.5f);
      idxf = fminf(fmaxf(idxf, 0.0f), 255.0f);
      float xs = -20.0f + idxf * delta;
      e = rintf((float)exp((double)xs) / EXP_SCALE_F);
    }
    e = fminf(fmaxf(e, -32768.0f), 32767.0f);
    exp_tab[t] = (int)e;

    const float RECIP_SCALE_F = (float)((1.0 / 0.1) * 2.0 / 65535.0);
    float deltar = (250.0f - 0.1f) / 255.0f;
    float xs = 0.1f + (float)t * deltar;
    float r = rintf((1.0f / xs) / RECIP_SCALE_F);
    r = fminf(fmaxf(r, -32768.0f), 32767.0f);
    recip_tab[t] = r;
  }

  // ---- load 8 channels x 4 pixels; pack to 4x int8 per int; local max ----
  const int4* g4 = (const int4*)data;
  int pd[8];                         // packed raw data, 8 VGPRs
  int4 m = make_int4(-128, -128, -128, -128);
#pragma unroll
  for (int i = 0; i < 8; ++i) {
    int4 v = g4[base4 + (16 * i + k) * (NHW / 4) + p4];
    m.x = max(m.x, v.x); m.y = max(m.y, v.y);
    m.z = max(m.z, v.z); m.w = max(m.w, v.w);
    pd[i] = (v.x & 255) | ((v.y & 255) << 8) | ((v.z & 255) << 16) |
            (int)((unsigned)(v.w & 255) << 24);
  }
  red_m[k][p4] = m;
  __syncthreads();

  // ---- every thread reduces the 16 partial maxes (broadcast b128 reads) ----
  int4 q = red_m[0][p4];
#pragma unroll
  for (int kk = 1; kk < 16; ++kk) {
    int4 r = red_m[kk][p4];
    q.x = max(q.x, r.x); q.y = max(q.y, r.y);
    q.z = max(q.z, r.z); q.w = max(q.w, r.w);
  }

  // ---- exp LUT gather + pack exp (u16 pairs) + channel partial sum ----
  int pe[16];                        // packed exp, 16 VGPRs
  int4 s = make_int4(0, 0, 0, 0);
#pragma unroll
  for (int i = 0; i < 8; ++i) {
    int pdv = pd[i];
    int c0 = (pdv << 24) >> 24;
    int c1 = (pdv << 16) >> 24;
    int c2 = (pdv << 8) >> 24;
    int c3 = pdv >> 24;
    int e0 = exp_tab[q.x - c0];      // j guaranteed in [0,255]
    int e1 = exp_tab[q.y - c1];
    int e2 = exp_tab[q.z - c2];
    int e3 = exp_tab[q.w - c3];
    s.x += e0; s.y += e1; s.z += e2; s.w += e3;
    pe[2 * i]     = e0 | (e1 << 16); // e in [0,32767] -> fits u16, sign-safe
    pe[2 * i + 1] = e2 | (e3 << 16);
  }
  red_s[k][p4] = s;
  __syncthreads();

  // ---- every thread reduces the 16 partial sums, then recip (redundant) ----
  int4 tot = red_s[0][p4];
#pragma unroll
  for (int kk = 1; kk < 16; ++kk) {
    int4 r = red_s[kk][p4];
    tot.x += r.x; tot.y += r.y; tot.z += r.z; tot.w += r.w;
  }
  const float DIV_SCALE_F = (float)((2.0 / 65535.0) * 128.0); // exp_scale * 2^7
  const float RIDX_K_F    = (float)(255.0 / (250.0 - 0.1));
  float rq[4];
  {
    int tv[4] = {tot.x, tot.y, tot.z, tot.w};
#pragma unroll
    for (int j = 0; j < 4; ++j) {
      float ss = rintf((float)tv[j] * 0.0078125f);
      ss = fminf(fmaxf(ss, -32768.0f), 32767.0f);
      float v = ss * DIV_SCALE_F;
      float idxf = rintf((v - 0.1f) * RIDX_K_F);
      idxf = fminf(fmaxf(idxf, 0.0f), 255.0f);
      rq[j] = recip_tab[(int)idxf];
    }
  }

  // ---- epilogue: out = clip(round((e*r)*K), -128, 127) * OUT_SCALE ----
  const float K_F = (float)((2.0 / 65535.0) * ((1.0 / 0.1) * 2.0 / 65535.0) / (2.0 / 255.0));
  const float OUT_SCALE_F = (float)(2.0 / 255.0);
  vfloat4* o4 = (vfloat4*)out;
#pragma unroll
  for (int i = 0; i < 8; ++i) {
    int pa = pe[2 * i], pb = pe[2 * i + 1];
    float e0 = (float)(pa & 0xFFFF);
    float e1 = (float)(pa >> 16);
    float e2 = (float)(pb & 0xFFFF);
    float e3 = (float)(pb >> 16);
    vfloat4 o;
    o.x = fminf(fmaxf(rintf((e0 * rq[0]) * K_F), -128.0f), 127.0f) * OUT_SCALE_F;
    o.y = fminf(fmaxf(rintf((e1 * rq[1]) * K_F), -128.0f), 127.0f) * OUT_SCALE_F;
    o.z = fminf(fmaxf(rintf((e2 * rq[2]) * K_F), -128.0f), 127.0f) * OUT_SCALE_F;
    o.w = fminf(fmaxf(rintf((e3 * rq[3]) * K_F), -128.0f), 127.0f) * OUT_SCALE_F;
    o4[base4 + (16 * i + k) * (NHW / 4) + p4] = o;   // plain cached store
  }
}

extern "C" void kernel_launch(void* const* d_in, const int* in_sizes, int n_in,
                              void* d_out, int out_size, void* d_ws, size_t ws_size,
                              hipStream_t stream) {
  const int* data     = (const int*)d_in[0];
  const float* dscale = (const float*)d_in[1];
  float* out          = (float*)d_out;
  (void)in_sizes; (void)n_in; (void)d_ws; (void)ws_size; (void)out_size;

  dim3 grid(NB * (NHW / PIX));   // 32 * 100 = 3200 blocks
  qsoftmax_kernel<<<grid, TPB, 0, stream>>>(data, dscale, out);
}